// Round 11
// baseline (2045.428 us; speedup 1.0000x reference)
//
#include <hip/hip_runtime.h>
#include <hip/hip_fp16.h>
#include <math.h>

// GraphGPS GatedGCN stack, fused single cooperative kernel. R11:
// = R9 dataflow (gather + fp16 sigma, global wT, merged GEMM phase), at
//   TPB 1024 with STATIC __shared__ (145KB). Static LDS makes occupancy
//   (1 block/CU) visible to the register allocator -> VGPR budget 128 at
//   16 waves (was 64 with blind 2-block assumption => R5-R7 spills).
// - Edge tile: 2 edges x 9 cols (acc 18). Node tile: 18 cols x k-half
//   (acc 18, one shfl_xor(32) combine). Lean live sets, no spill at 128.
// - 6 local barriers + 1 grid barrier per layer.

#define TPB 1024
#define NBLK 256
#define DD 70
#define ETS 256      // eT row stride (dwords)
#define NBS 84       // node-buffer row stride
#define WTS 80       // wT row stride (k-padded)
#define NLAYERS 17
#define SPL 280
#define NSLOT 8
#define EPS_AGG 1e-6f
#define EPS_BN 1e-5f
#define EPS_LN 1e-5f

#define SCX 0
#define SHX 72
#define SCE 144
#define SHE 216
#define SBO 288
#define STATL_F 576

#define OFF_ET   0
#define OFF_HN   (OFF_ET + 72*ETS)            // 18432
#define OFF_AX   (OFF_HN + 32*NBS)
#define OFF_BX   (OFF_AX + 32*NBS)
#define OFF_DX   (OFF_BX + 32*NBS)            // sigma overlay starts here
#define OFF_EX   (OFF_DX + 32*NBS)
#define OFF_PAD  (OFF_EX + 32*NBS)            // sigma spillover (8960 dwords total)
#define OFF_STATL (OFF_PAD + 3584)
#define SMEM_FLOATS (OFF_STATL + STATL_F)     // 36032 floats = 144128 B

// swizzled eT index (dwords): row k, edge e; permutes 16B blocks
#define EIX(k,e) (((k)<<8) + ((e) ^ ((((k)>>2)&7)<<2)))
// sigma dword index: feature j, dword-col c (= e/2)
#define SIX(j,c) (((j)<<7) + ((c) ^ ((j)&30)))

// d_ws layout
#define WS_STATS 4096
#define WS_WT    163840

struct GPSParams {
  const float* __restrict__ x; const int* __restrict__ ei; const float* __restrict__ ea;
  const float* __restrict__ wn; const float* __restrict__ bnn;
  const float* __restrict__ we; const float* __restrict__ web;
  const float* __restrict__ Aw[2]; const float* __restrict__ Ab[2];
  const float* __restrict__ Bw[2]; const float* __restrict__ Bb[2];
  const float* __restrict__ Cw[2]; const float* __restrict__ Cb[2];
  const float* __restrict__ Dw[2]; const float* __restrict__ Db[2];
  const float* __restrict__ Ew[2]; const float* __restrict__ Eb[2];
  const float* __restrict__ gx[2]; const float* __restrict__ bx[2];
  const float* __restrict__ ge[2]; const float* __restrict__ gbe[2];
  const float* __restrict__ c1w; const float* __restrict__ c1b;
  const float* __restrict__ lng; const float* __restrict__ lnb;
  const float* __restrict__ c2w; const float* __restrict__ c2b;
  float* __restrict__ out; float* __restrict__ stats; float* __restrict__ wt;
  unsigned* __restrict__ bar;
};

__device__ __forceinline__ void grid_sync(unsigned* b) {
  __syncthreads();
  if (threadIdx.x == 0) {
    unsigned g = __hip_atomic_load(b, __ATOMIC_RELAXED, __HIP_MEMORY_SCOPE_AGENT);
    int leaf = (int)(blockIdx.x >> 4);
    unsigned a = __hip_atomic_fetch_add(b + 32 + leaf*32, 1u, __ATOMIC_ACQ_REL, __HIP_MEMORY_SCOPE_AGENT);
    bool done = false;
    if (a == 15u) {
      unsigned r = __hip_atomic_fetch_add(b + 16, 1u, __ATOMIC_ACQ_REL, __HIP_MEMORY_SCOPE_AGENT);
      if (r == 15u) {
        #pragma unroll
        for (int i2 = 0; i2 < 16; ++i2)
          __hip_atomic_store(b + 32 + i2*32, 0u, __ATOMIC_RELAXED, __HIP_MEMORY_SCOPE_AGENT);
        __hip_atomic_store(b + 16, 0u, __ATOMIC_RELAXED, __HIP_MEMORY_SCOPE_AGENT);
        __hip_atomic_store(b, g + 1u, __ATOMIC_RELEASE, __HIP_MEMORY_SCOPE_AGENT);
        done = true;
      }
    }
    if (!done) {
      while (__hip_atomic_load(b, __ATOMIC_ACQUIRE, __HIP_MEMORY_SCOPE_AGENT) == g)
        __builtin_amdgcn_s_sleep(2);
    }
  }
  __syncthreads();
}

__global__ void __launch_bounds__(TPB)
gps_kernel(GPSParams p) {
  __shared__ float smem[SMEM_FLOATS];      // STATIC: allocator sees 1 block/CU
  __shared__ int icur[32];
  __shared__ int ioff[33];
  __shared__ unsigned char srcloc[256];
  __shared__ unsigned char dstloc[256];
  __shared__ unsigned short eidxS[256];

  float* eT    = smem + OFF_ET;      // [72][256] e_old, swizzled; rows 70/71 = 0
  float* hN    = smem + OFF_HN;      // [32][84], cols >=70 zero
  float* Ax    = smem + OFF_AX;
  float* Bx    = smem + OFF_BX;
  float* Dx    = smem + OFF_DX;
  float* Ex    = smem + OFF_EX;
  float* statl = smem + OFF_STATL;
  unsigned* sigb = (unsigned*)(smem + OFF_DX);   // sigma fp16: 70*128 dwords
  const __half* sigh = (const __half*)sigb;

  const int tid  = threadIdx.x;
  const int g    = blockIdx.x;
  const int lane = tid & 63;
  const int wid  = tid >> 6;          // 0..15

  // edge roles: wave -> (half, 9-col group); thread -> 2 edges
  const int e_cg = wid & 7;
  const int jbe  = e_cg * 9;
  const int e0   = (((wid >> 3) << 6) | lane) << 1;   // even, 0..254
  // node roles: wave -> (matrix m, 18-col group); lane -> (k-half, node)
  const int n_m  = wid & 3;
  const int n_jb = (wid >> 2) * 18;
  const int n_kh = lane >> 5;
  const int n_n  = lane & 31;
  const int n_k0 = n_kh * 40;

  float* slot = p.stats + ((g & 7) * NLAYERS) * SPL;

  // ---------------- CSR build ----------------
  if (tid < 32) icur[tid] = 0;
  __syncthreads();
  if (tid < 256) {
    int s0 = p.ei[g*256 + tid]         - g*32;
    int d0 = p.ei[65536 + g*256 + tid] - g*32;
    srcloc[tid] = (unsigned char)s0;
    dstloc[tid] = (unsigned char)d0;
    atomicAdd(&icur[d0], 1);
  }
  __syncthreads();
  if (tid == 0) {
    int o = 0;
    for (int n = 0; n < 32; ++n) { ioff[n] = o; o += icur[n]; }
    ioff[32] = o;
  }
  __syncthreads();
  if (tid < 32) icur[tid] = ioff[tid];
  __syncthreads();
  if (tid < 256) {
    int d0 = dstloc[tid];
    int sl2 = atomicAdd(&icur[d0], 1);
    eidxS[sl2] = (unsigned short)(tid | ((int)srcloc[tid] << 8));
  }

  // ---------------- init ----------------
  for (int i = tid; i < SMEM_FLOATS - OFF_HN; i += TPB) smem[OFF_HN + i] = 0.f;
  for (int i = tid; i < 2*ETS; i += TPB) eT[70*ETS + i] = 0.f;  // pad rows
  __syncthreads();
  for (int i = tid; i < 32*DD; i += TPB) {
    int n = i / DD, j = i % DD;
    hN[n*NBS + j] = fmaf(p.x[g*32 + n], p.wn[j], p.bnn[j]);
  }
  for (int i = tid; i < DD*256; i += TPB) {
    int k = i >> 8, e = i & 255;
    eT[EIX(k, e)] = fmaf(p.ea[g*256 + e], p.we[k], p.web[k]);
  }

  // ---------------- weight transpose pre-pass (blocks 0..9) ----------------
  if (g < 10) {
    int ss = g / 5, mm = g % 5;
    const float* W = (mm==0) ? p.Aw[ss] : (mm==1) ? p.Bw[ss] : (mm==2) ? p.Cw[ss]
                   : (mm==3) ? p.Dw[ss] : p.Ew[ss];
    float* dst = p.wt + g * (72*WTS);
    for (int i = tid; i < 72*WTS; i += TPB) {
      int j = i / WTS, k = i - j*WTS;
      dst[i] = (j < DD && k < DD) ? W[k*DD + j] : 0.f;
    }
  }
  grid_sync(p.bar);   // wT visible; local init done

  // ---------------- layer loop ----------------
  #pragma unroll 1
  for (int L = 0; L < NLAYERS; ++L) {
    const int s = (L == 0) ? 0 : 1;
    float* lslot = slot + L * SPL;
    const float* wbase = p.wt + (size_t)(s*5) * (72*WTS);

    // ---- phase A: biases + node GEMMs + edge GEMM (no internal barrier) ----
    if (tid < DD) statl[SBO + tid] = p.Cb[s][tid] + p.Db[s][tid] + p.Eb[s][tid];

    { // node GEMMs: 4 matrices x 4 col-groups across 16 waves
      const float* Wm = wbase + ((n_m==0) ? 0 : (n_m==1) ? 1 : (n_m==2) ? 3 : 4) * (72*WTS);
      float* nbuf = (n_m==0) ? Ax : (n_m==1) ? Bx : (n_m==2) ? Dx : Ex;
      const float* nbias = (n_m==1) ? p.Bb[s] : p.Ab[s];
      float acc[18];
      #pragma unroll
      for (int i = 0; i < 18; ++i) acc[i] = 0.f;
      const float* hrow = hN + n_n*NBS + n_k0;
      #pragma unroll 1
      for (int c = 0; c < 5; ++c) {
        float4 ha = *(const float4*)(hrow + c*8);
        float4 hb = *(const float4*)(hrow + c*8 + 4);
        #pragma unroll
        for (int i = 0; i < 18; ++i) {
          const float* wr = Wm + (n_jb + i)*WTS + n_k0 + c*8;
          float4 wa = *(const float4*)(wr);
          float4 wb = *(const float4*)(wr + 4);
          acc[i] = fmaf(ha.x, wa.x, acc[i]); acc[i] = fmaf(ha.y, wa.y, acc[i]);
          acc[i] = fmaf(ha.z, wa.z, acc[i]); acc[i] = fmaf(ha.w, wa.w, acc[i]);
          acc[i] = fmaf(hb.x, wb.x, acc[i]); acc[i] = fmaf(hb.y, wb.y, acc[i]);
          acc[i] = fmaf(hb.z, wb.z, acc[i]); acc[i] = fmaf(hb.w, wb.w, acc[i]);
        }
      }
      #pragma unroll
      for (int i = 0; i < 18; ++i) acc[i] += __shfl_xor(acc[i], 32, 64);
      if (n_kh == 0) {
        #pragma unroll
        for (int i = 0; i < 18; ++i) {
          int j = n_jb + i;
          if (j < DD) {
            float b = (n_m < 2) ? nbias[j] : 0.f;
            nbuf[n_n*NBS + j] = acc[i] + b;
          }
        }
      }
    }

    // edge GEMM: eacc[r][i] = sum_k eold[e0+r][k] * Cw[k][jbe+i]
    const float* wC = wbase + 2 * (72*WTS);
    float eacc[2][9];
    #pragma unroll
    for (int r = 0; r < 2; ++r)
      #pragma unroll
      for (int i = 0; i < 9; ++i) eacc[r][i] = 0.f;

    #pragma unroll 1
    for (int c = 0; c < 9; ++c) {
      const int k0 = c*8;
      float2 ev[8];
      #pragma unroll
      for (int kk = 0; kk < 8; ++kk)
        ev[kk] = *(const float2*)(eT + EIX(k0 + kk, e0));
      #pragma unroll
      for (int i = 0; i < 9; ++i) {
        const float* wr = wC + (jbe + i)*WTS + k0;
        float4 wa = *(const float4*)(wr);
        float4 wb = *(const float4*)(wr + 4);
        eacc[0][i] = fmaf(ev[0].x, wa.x, eacc[0][i]); eacc[1][i] = fmaf(ev[0].y, wa.x, eacc[1][i]);
        eacc[0][i] = fmaf(ev[1].x, wa.y, eacc[0][i]); eacc[1][i] = fmaf(ev[1].y, wa.y, eacc[1][i]);
        eacc[0][i] = fmaf(ev[2].x, wa.z, eacc[0][i]); eacc[1][i] = fmaf(ev[2].y, wa.z, eacc[1][i]);
        eacc[0][i] = fmaf(ev[3].x, wa.w, eacc[0][i]); eacc[1][i] = fmaf(ev[3].y, wa.w, eacc[1][i]);
        eacc[0][i] = fmaf(ev[4].x, wb.x, eacc[0][i]); eacc[1][i] = fmaf(ev[4].y, wb.x, eacc[1][i]);
        eacc[0][i] = fmaf(ev[5].x, wb.y, eacc[0][i]); eacc[1][i] = fmaf(ev[5].y, wb.y, eacc[1][i]);
        eacc[0][i] = fmaf(ev[6].x, wb.z, eacc[0][i]); eacc[1][i] = fmaf(ev[6].y, wb.z, eacc[1][i]);
        eacc[0][i] = fmaf(ev[7].x, wb.w, eacc[0][i]); eacc[1][i] = fmaf(ev[7].y, wb.w, eacc[1][i]);
      }
    }
    __syncthreads();   // S1: Ax/Bx/Dx/Ex + SBO ready

    // ---- phase B: e-finish + e-stats ----
    {
      int dl0 = dstloc[e0],   sl0 = srcloc[e0];
      int dl1 = dstloc[e0+1], sl1 = srcloc[e0+1];
      const float* dx0 = Dx + dl0*NBS; const float* ex0 = Ex + sl0*NBS;
      const float* dx1 = Dx + dl1*NBS; const float* ex1 = Ex + sl1*NBS;
      #pragma unroll
      for (int i = 0; i < 9; ++i) {
        int j = jbe + i;
        float bb = statl[SBO + j];
        eacc[0][i] += dx0[j] + ex0[j] + bb;
        eacc[1][i] += dx1[j] + ex1[j] + bb;
      }
    }
    #pragma unroll
    for (int i = 0; i < 9; ++i) {
      int j = jbe + i;
      float ps = eacc[0][i] + eacc[1][i];
      float qs = fmaf(eacc[0][i], eacc[0][i], eacc[1][i]*eacc[1][i]);
      #pragma unroll
      for (int d = 1; d < 64; d <<= 1) {
        ps += __shfl_xor(ps, d, 64);
        qs += __shfl_xor(qs, d, 64);
      }
      if (lane == 0 && j < DD) {
        atomicAdd(lslot + 140 + j, ps);
        atomicAdd(lslot + 210 + j, qs);
      }
    }
    __syncthreads();   // S2: all Dx/Ex reads done (sigma overlays them)

    // sigma -> fp16 side buffer (overlays Dx/Ex/PAD)
    #pragma unroll
    for (int i = 0; i < 9; ++i) {
      int j = jbe + i;
      if (j < DD) {
        float s0 = 1.f / (1.f + __expf(-eacc[0][i]));
        float s1 = 1.f / (1.f + __expf(-eacc[1][i]));
        __half2 h01 = __floats2half2_rn(s0, s1);
        sigb[SIX(j, e0 >> 1)] = *reinterpret_cast<unsigned*>(&h01);
      }
    }
    __syncthreads();   // S3

    // ---- gather: x_new = Ax + num/den (RMW into Ax), 2-way edge split ----
    {
      auto gath = [&](int item, int sub) {
        int n = item / 18, jq = item % 18;
        int j0 = jq * 4;
        bool v2 = (j0 + 2) < DD, v3 = (j0 + 3) < DD;
        float nm0 = 0.f, nm1 = 0.f, nm2 = 0.f, nm3 = 0.f;
        float dn0 = 0.f, dn1 = 0.f, dn2 = 0.f, dn3 = 0.f;
        int pb = ioff[n], pe = ioff[n + 1];
        int mid = (pb + pe + 1) >> 1;
        int lo = sub ? mid : pb;
        int hi = sub ? pe : mid;
        for (int pp = lo; pp < hi; ++pp) {
          unsigned v = eidxS[pp];
          int e2 = v & 255, sl2 = v >> 8;
          int cb = e2 >> 1, h2 = e2 & 1;
          float s0 = __half2float(sigh[(SIX(j0+0, cb) << 1) + h2]);
          float s1 = __half2float(sigh[(SIX(j0+1, cb) << 1) + h2]);
          float s2 = v2 ? __half2float(sigh[(SIX(j0+2, cb) << 1) + h2]) : 0.f;
          float s3 = v3 ? __half2float(sigh[(SIX(j0+3, cb) << 1) + h2]) : 0.f;
          float4 b4 = *(const float4*)(Bx + sl2*NBS + j0);
          nm0 = fmaf(s0, b4.x, nm0); nm1 = fmaf(s1, b4.y, nm1);
          nm2 = fmaf(s2, b4.z, nm2); nm3 = fmaf(s3, b4.w, nm3);
          dn0 += s0; dn1 += s1; dn2 += s2; dn3 += s3;
        }
        nm0 += __shfl_xor(nm0, 1, 64); dn0 += __shfl_xor(dn0, 1, 64);
        nm1 += __shfl_xor(nm1, 1, 64); dn1 += __shfl_xor(dn1, 1, 64);
        nm2 += __shfl_xor(nm2, 1, 64); dn2 += __shfl_xor(dn2, 1, 64);
        nm3 += __shfl_xor(nm3, 1, 64); dn3 += __shfl_xor(dn3, 1, 64);
        if (sub == 0) {
          float* axp = Ax + n*NBS + j0;
          float4 ax = *(const float4*)axp;
          ax.x += nm0 / (dn0 + EPS_AGG);
          ax.y += nm1 / (dn1 + EPS_AGG);
          ax.z += nm2 / (dn2 + EPS_AGG);
          ax.w += nm3 / (dn3 + EPS_AGG);
          *(float4*)axp = ax;
        }
      };
      gath(tid >> 1, tid & 1);                          // items 0..511
      if (tid < 128) gath(512 + (tid >> 1), tid & 1);   // items 512..575
    }
    __syncthreads();   // S4

    // x-stats (280 threads: 70 cols x 4 node-quarters)
    if (tid < SPL) {
      int col = tid % DD, q = tid / DD;
      float sm = 0.f, sq = 0.f;
      #pragma unroll
      for (int r = 0; r < 8; ++r) {
        float v = Ax[(q*8 + r)*NBS + col];
        sm += v; sq = fmaf(v, v, sq);
      }
      atomicAdd(lslot + col, sm);
      atomicAdd(lslot + 70 + col, sq);
    }

    grid_sync(p.bar);

    // BN scale/shift from 8 slots
    if (tid < DD) {
      float sm = 0.f, sq = 0.f;
      #pragma unroll
      for (int sl2 = 0; sl2 < NSLOT; ++sl2) {
        const float* st = p.stats + (sl2*NLAYERS + L)*SPL;
        sm += __hip_atomic_load(st + tid,      __ATOMIC_RELAXED, __HIP_MEMORY_SCOPE_AGENT);
        sq += __hip_atomic_load(st + 70 + tid, __ATOMIC_RELAXED, __HIP_MEMORY_SCOPE_AGENT);
      }
      float mean = sm * (1.f/8192.f);
      float var  = sq * (1.f/8192.f) - mean*mean;
      float sc = p.gx[s][tid] * rsqrtf(var + EPS_BN);
      statl[SCX + tid] = sc;
      statl[SHX + tid] = fmaf(-mean, sc, p.bx[s][tid]);
    } else if (tid < 140) {
      int j = tid - DD;
      float sm = 0.f, sq = 0.f;
      #pragma unroll
      for (int sl2 = 0; sl2 < NSLOT; ++sl2) {
        const float* st = p.stats + (sl2*NLAYERS + L)*SPL;
        sm += __hip_atomic_load(st + 140 + j, __ATOMIC_RELAXED, __HIP_MEMORY_SCOPE_AGENT);
        sq += __hip_atomic_load(st + 210 + j, __ATOMIC_RELAXED, __HIP_MEMORY_SCOPE_AGENT);
      }
      float mean = sm * (1.f/65536.f);
      float var  = sq * (1.f/65536.f) - mean*mean;
      float sc = p.ge[s][j] * rsqrtf(var + EPS_BN);
      statl[SCE + j] = sc;
      statl[SHE + j] = fmaf(-mean, sc, p.gbe[s][j]);
    }
    __syncthreads();   // S5

    // apply BN+ReLU+residual: h (2304 elems)
    #pragma unroll
    for (int r = 0; r < 3; ++r) {
      int idx = tid + r*TPB;
      if (idx < 2304) {
        int n = idx / 72, j = idx - n*72;
        if (j < DD) {
          float xn = Ax[n*NBS + j];
          hN[n*NBS + j] += fmaxf(fmaf(xn, statl[SCX + j], statl[SHX + j]), 0.f);
        }
      }
    }
    // apply BN+ReLU+residual: e — e_old re-read from eT (kept intact), b64 RMW
    #pragma unroll
    for (int i = 0; i < 9; ++i) {
      int j = jbe + i;
      if (j < DD) {
        float sc = statl[SCE + j], sh = statl[SHE + j];
        float* ep = eT + EIX(j, e0);
        float2 eo = *(const float2*)ep;
        eo.x += fmaxf(fmaf(eacc[0][i], sc, sh), 0.f);
        eo.y += fmaxf(fmaf(eacc[1][i], sc, sh), 0.f);
        *(float2*)ep = eo;
      }
    }
    __syncthreads();   // S6
  }

  // ---------------- readout ----------------
  if (tid < DD) {
    float mx = -3.4e38f, sm = 0.f;
    #pragma unroll 4
    for (int r = 0; r < 32; ++r) {
      float v = hN[r*NBS + tid];
      mx = fmaxf(mx, v); sm += v;
    }
    statl[tid]      = mx;               // gmp
    statl[70 + tid] = sm * (1.f/32.f);  // gap
  }
  __syncthreads();
  if (tid < 256) {
    float a = p.c1b[tid];
    for (int k = 0; k < DD; ++k) a = fmaf(statl[k],      p.c1w[k*256 + tid], a);
    for (int k = 0; k < DD; ++k) a = fmaf(statl[70 + k], p.c1w[(DD + k)*256 + tid], a);
    Ax[tid] = fmaxf(a, 0.f);
  }
  __syncthreads();
  if (tid == 0) {
    float sm = 0.f, sq = 0.f;
    for (int k = 0; k < 256; ++k) { float v = Ax[k]; sm += v; sq = fmaf(v, v, sq); }
    float mean = sm * (1.f/256.f);
    float var  = sq * (1.f/256.f) - mean*mean;
    statl[560] = mean;
    statl[561] = rsqrtf(var + EPS_LN);
  }
  __syncthreads();
  if (tid < 256) {
    float v = (Ax[tid] - statl[560]) * statl[561];
    Bx[tid] = fmaf(v, p.lng[tid], p.lnb[tid]);
  }
  __syncthreads();
  if (tid < 10) {
    float a = p.c2b[tid];
    for (int k = 0; k < 256; ++k) a = fmaf(Bx[k], p.c2w[k*10 + tid], a);
    p.out[g*10 + tid] = a;
  }
}

extern "C" void kernel_launch(void* const* d_in, const int* in_sizes, int n_in,
                              void* d_out, int out_size, void* d_ws, size_t ws_size,
                              hipStream_t stream) {
  (void)in_sizes; (void)n_in; (void)out_size; (void)ws_size;
  GPSParams p;
  p.x   = (const float*)d_in[0];
  p.ei  = (const int*)  d_in[1];
  p.ea  = (const float*)d_in[2];
  p.wn  = (const float*)d_in[4];  p.bnn = (const float*)d_in[5];
  p.we  = (const float*)d_in[6];  p.web = (const float*)d_in[7];
  int i = 8;
  for (int s = 0; s < 2; ++s) {
    p.Aw[s] = (const float*)d_in[i++]; p.Ab[s] = (const float*)d_in[i++];
    p.Bw[s] = (const float*)d_in[i++]; p.Bb[s] = (const float*)d_in[i++];
    p.Cw[s] = (const float*)d_in[i++]; p.Cb[s] = (const float*)d_in[i++];
    p.Dw[s] = (const float*)d_in[i++]; p.Db[s] = (const float*)d_in[i++];
    p.Ew[s] = (const float*)d_in[i++]; p.Eb[s] = (const float*)d_in[i++];
    p.gx[s] = (const float*)d_in[i++]; p.bx[s] = (const float*)d_in[i++];
    p.ge[s] = (const float*)d_in[i++]; p.gbe[s] = (const float*)d_in[i++];
  }
  p.c1w = (const float*)d_in[36]; p.c1b = (const float*)d_in[37];
  p.lng = (const float*)d_in[38]; p.lnb = (const float*)d_in[39];
  p.c2w = (const float*)d_in[40]; p.c2b = (const float*)d_in[41];
  p.out = (float*)d_out;
  p.bar = (unsigned*)d_ws;
  p.stats = (float*)((char*)d_ws + WS_STATS);
  p.wt    = (float*)((char*)d_ws + WS_WT);

  // zero barrier + stats (ws not re-poisoned between replays); wT fully
  // rewritten by the pre-pass each call.
  hipMemsetAsync(d_ws, 0, WS_STATS + NSLOT*NLAYERS*SPL*4, stream);

  void* args[] = { (void*)&p };
  hipError_t err = hipLaunchCooperativeKernel((const void*)gps_kernel,
                                              dim3(NBLK), dim3(TPB),
                                              args, 0, stream);
  if (err != hipSuccess) {
    gps_kernel<<<dim3(NBLK), dim3(TPB), 0, stream>>>(p);
  }
}

// Round 12
// 909.753 us; speedup vs baseline: 2.2483x; 2.2483x over previous
//
#include <hip/hip_runtime.h>
#include <hip/hip_fp16.h>
#include <math.h>

// GraphGPS GatedGCN stack, fused single cooperative kernel. R12:
// = R9 base (TPB 768, VGPR-safe 4x6 edge tile, global wT, gather), plus:
// - sigma stored EDGE-MAJOR fp16: sig[e][j], row stride 72 halves (36 dwords).
//   Gather reads sigma for 4 consecutive j in ONE b64 (was 4 scalar u16)
//   -> 3 LDS ops per gathered edge instead of 6.
// - Phase-B Dx/Ex reads as float2 (24 b64 vs 48 scalar).
// - Fixed 240B dynamic-LDS tail overflow present in R8/R9.

#define TPB 768
#define NBLK 256
#define DD 70
#define ETS 256      // eT row stride (dwords)
#define NBS 84       // node-buffer row stride
#define WTS 80       // wT row stride (k-padded)
#define SGS 36       // sigma row stride in dwords (72 halves)
#define NLAYERS 17
#define SPL 280
#define NSLOT 8
#define EPS_AGG 1e-6f
#define EPS_BN 1e-5f
#define EPS_LN 1e-5f

#define SCX 0
#define SHX 72
#define SCE 144
#define SHE 216
#define SBO 288
#define STATL_F 576

#define OFF_ET   0
#define OFF_HN   (OFF_ET + 72*ETS)            // 18432
#define OFF_AX   (OFF_HN + 32*NBS)
#define OFF_BX   (OFF_AX + 32*NBS)
#define OFF_DX   (OFF_BX + 32*NBS)            // sigma overlay starts here
#define OFF_EX   (OFF_DX + 32*NBS)
#define OFF_PAD  (OFF_EX + 32*NBS)            // overlay spillover
#define OFF_STATL (OFF_DX + 256*SGS)          // = OFF_DX + 9216
#define SMEM_FLOATS (OFF_STATL + STATL_F)     // 36288 floats = 145152 B
#define SMEM_BYTES  (SMEM_FLOATS*4 + 2048)

// swizzled eT index (dwords): row k, edge e; permutes 16B blocks
#define EIX(k,e) (((k)<<8) + ((e) ^ ((((k)>>2)&7)<<2)))

// d_ws layout
#define WS_STATS 4096
#define WS_WT    163840

struct GPSParams {
  const float* __restrict__ x; const int* __restrict__ ei; const float* __restrict__ ea;
  const float* __restrict__ wn; const float* __restrict__ bnn;
  const float* __restrict__ we; const float* __restrict__ web;
  const float* __restrict__ Aw[2]; const float* __restrict__ Ab[2];
  const float* __restrict__ Bw[2]; const float* __restrict__ Bb[2];
  const float* __restrict__ Cw[2]; const float* __restrict__ Cb[2];
  const float* __restrict__ Dw[2]; const float* __restrict__ Db[2];
  const float* __restrict__ Ew[2]; const float* __restrict__ Eb[2];
  const float* __restrict__ gx[2]; const float* __restrict__ bx[2];
  const float* __restrict__ ge[2]; const float* __restrict__ gbe[2];
  const float* __restrict__ c1w; const float* __restrict__ c1b;
  const float* __restrict__ lng; const float* __restrict__ lnb;
  const float* __restrict__ c2w; const float* __restrict__ c2b;
  float* __restrict__ out; float* __restrict__ stats; float* __restrict__ wt;
  unsigned* __restrict__ bar;
};

__device__ __forceinline__ void grid_sync(unsigned* b) {
  __syncthreads();
  if (threadIdx.x == 0) {
    unsigned g = __hip_atomic_load(b, __ATOMIC_RELAXED, __HIP_MEMORY_SCOPE_AGENT);
    int leaf = (int)(blockIdx.x >> 4);
    unsigned a = __hip_atomic_fetch_add(b + 32 + leaf*32, 1u, __ATOMIC_ACQ_REL, __HIP_MEMORY_SCOPE_AGENT);
    bool done = false;
    if (a == 15u) {
      unsigned r = __hip_atomic_fetch_add(b + 16, 1u, __ATOMIC_ACQ_REL, __HIP_MEMORY_SCOPE_AGENT);
      if (r == 15u) {
        #pragma unroll
        for (int i2 = 0; i2 < 16; ++i2)
          __hip_atomic_store(b + 32 + i2*32, 0u, __ATOMIC_RELAXED, __HIP_MEMORY_SCOPE_AGENT);
        __hip_atomic_store(b + 16, 0u, __ATOMIC_RELAXED, __HIP_MEMORY_SCOPE_AGENT);
        __hip_atomic_store(b, g + 1u, __ATOMIC_RELEASE, __HIP_MEMORY_SCOPE_AGENT);
        done = true;
      }
    }
    if (!done) {
      while (__hip_atomic_load(b, __ATOMIC_ACQUIRE, __HIP_MEMORY_SCOPE_AGENT) == g)
        __builtin_amdgcn_s_sleep(2);
    }
  }
  __syncthreads();
}

__global__ void __launch_bounds__(TPB)
__attribute__((amdgpu_waves_per_eu(3, 3)))
gps_kernel(GPSParams p) {
  extern __shared__ float smem[];
  float* eT    = smem + OFF_ET;      // [72][256] e_old, swizzled; rows 70/71 = 0
  float* hN    = smem + OFF_HN;      // [32][84], cols >=70 zero
  float* Ax    = smem + OFF_AX;
  float* Bx    = smem + OFF_BX;
  float* Dx    = smem + OFF_DX;
  float* Ex    = smem + OFF_EX;
  float* statl = smem + OFF_STATL;
  unsigned* sigb = (unsigned*)(smem + OFF_DX);   // sigma fp16 [256][36 dw]
  int*   icur  = (int*)(smem + SMEM_FLOATS);
  int*   ioff  = icur + 32;
  unsigned char* srcloc = (unsigned char*)(ioff + 33);
  unsigned char* dstloc = srcloc + 256;
  unsigned short* eidxS = (unsigned short*)(dstloc + 256);

  const int tid  = threadIdx.x;
  const int g    = blockIdx.x;
  const int lane = tid & 63;
  const int wid  = tid >> 6;          // 0..11

  // edge roles: wave = 6-col group, lane = 4-edge block
  const int jbe = wid * 6;
  const int e0  = lane * 4;
  // node roles: wave = (matrix m, col-group); thread = 3 cols x 4 nodes, full k
  const int n_m  = wid & 3;
  const int n_jb = (wid >> 2) * 24 + (lane >> 3) * 3;
  const int n_n0 = (lane & 7) * 4;

  float* slot = p.stats + ((g & 7) * NLAYERS) * SPL;

  // ---------------- CSR build ----------------
  if (tid < 32) icur[tid] = 0;
  __syncthreads();
  if (tid < 256) {
    int s0 = p.ei[g*256 + tid]         - g*32;
    int d0 = p.ei[65536 + g*256 + tid] - g*32;
    srcloc[tid] = (unsigned char)s0;
    dstloc[tid] = (unsigned char)d0;
    atomicAdd(&icur[d0], 1);
  }
  __syncthreads();
  if (tid == 0) {
    int o = 0;
    for (int n = 0; n < 32; ++n) { ioff[n] = o; o += icur[n]; }
    ioff[32] = o;
  }
  __syncthreads();
  if (tid < 32) icur[tid] = ioff[tid];
  __syncthreads();
  if (tid < 256) {
    int d0 = dstloc[tid];
    int sl2 = atomicAdd(&icur[d0], 1);
    eidxS[sl2] = (unsigned short)(tid | ((int)srcloc[tid] << 8));
  }

  // ---------------- init ----------------
  for (int i = tid; i < SMEM_FLOATS - OFF_HN; i += TPB) smem[OFF_HN + i] = 0.f;
  for (int i = tid; i < 2*ETS; i += TPB) eT[70*ETS + i] = 0.f;  // pad rows
  __syncthreads();
  for (int i = tid; i < 32*DD; i += TPB) {
    int n = i / DD, j = i % DD;
    hN[n*NBS + j] = fmaf(p.x[g*32 + n], p.wn[j], p.bnn[j]);
  }
  for (int i = tid; i < DD*256; i += TPB) {
    int k = i >> 8, e = i & 255;
    eT[EIX(k, e)] = fmaf(p.ea[g*256 + e], p.we[k], p.web[k]);
  }

  // ---------------- weight transpose pre-pass (blocks 0..9) ----------------
  if (g < 10) {
    int ss = g / 5, mm = g % 5;
    const float* W = (mm==0) ? p.Aw[ss] : (mm==1) ? p.Bw[ss] : (mm==2) ? p.Cw[ss]
                   : (mm==3) ? p.Dw[ss] : p.Ew[ss];
    float* dst = p.wt + g * (72*WTS);
    for (int i = tid; i < 72*WTS; i += TPB) {
      int j = i / WTS, k = i - j*WTS;
      dst[i] = (j < DD && k < DD) ? W[k*DD + j] : 0.f;
    }
  }
  grid_sync(p.bar);   // wT visible; local init done

  // ---------------- layer loop ----------------
  #pragma unroll 1
  for (int L = 0; L < NLAYERS; ++L) {
    const int s = (L == 0) ? 0 : 1;
    float* lslot = slot + L * SPL;
    const float* wbase = p.wt + (size_t)(s*5) * (72*WTS);

    // ---- phase A: biases + node GEMMs + edge GEMM (no internal barrier) ----
    if (tid < DD) statl[SBO + tid] = p.Cb[s][tid] + p.Db[s][tid] + p.Eb[s][tid];

    { // node GEMMs: all 4 matrices concurrently (wave -> matrix)
      const float* Wm = wbase + ((n_m==0) ? 0 : (n_m==1) ? 1 : (n_m==2) ? 3 : 4) * (72*WTS);
      float* nbuf = (n_m==0) ? Ax : (n_m==1) ? Bx : (n_m==2) ? Dx : Ex;
      const float* nbias = (n_m==1) ? p.Bb[s] : p.Ab[s];
      float acc[3][4];
      #pragma unroll
      for (int i = 0; i < 3; ++i)
        #pragma unroll
        for (int n = 0; n < 4; ++n) acc[i][n] = 0.f;
      const float* hr0 = hN + n_n0*NBS;
      #pragma unroll 2
      for (int c = 0; c < 18; ++c) {
        const int k0 = c*4;
        float4 h0 = *(const float4*)(hr0 + 0*NBS + k0);
        float4 h1 = *(const float4*)(hr0 + 1*NBS + k0);
        float4 h2 = *(const float4*)(hr0 + 2*NBS + k0);
        float4 h3 = *(const float4*)(hr0 + 3*NBS + k0);
        #pragma unroll
        for (int i = 0; i < 3; ++i) {
          float4 w4 = *(const float4*)(Wm + (n_jb + i)*WTS + k0);
          acc[i][0] = fmaf(h0.x, w4.x, acc[i][0]); acc[i][0] = fmaf(h0.y, w4.y, acc[i][0]);
          acc[i][0] = fmaf(h0.z, w4.z, acc[i][0]); acc[i][0] = fmaf(h0.w, w4.w, acc[i][0]);
          acc[i][1] = fmaf(h1.x, w4.x, acc[i][1]); acc[i][1] = fmaf(h1.y, w4.y, acc[i][1]);
          acc[i][1] = fmaf(h1.z, w4.z, acc[i][1]); acc[i][1] = fmaf(h1.w, w4.w, acc[i][1]);
          acc[i][2] = fmaf(h2.x, w4.x, acc[i][2]); acc[i][2] = fmaf(h2.y, w4.y, acc[i][2]);
          acc[i][2] = fmaf(h2.z, w4.z, acc[i][2]); acc[i][2] = fmaf(h2.w, w4.w, acc[i][2]);
          acc[i][3] = fmaf(h3.x, w4.x, acc[i][3]); acc[i][3] = fmaf(h3.y, w4.y, acc[i][3]);
          acc[i][3] = fmaf(h3.z, w4.z, acc[i][3]); acc[i][3] = fmaf(h3.w, w4.w, acc[i][3]);
        }
      }
      #pragma unroll
      for (int i = 0; i < 3; ++i) {
        int j = n_jb + i;
        if (j < DD) {
          float b = (n_m < 2) ? nbias[j] : 0.f;
          #pragma unroll
          for (int n = 0; n < 4; ++n)
            nbuf[(n_n0 + n)*NBS + j] = acc[i][n] + b;
        }
      }
    }

    // edge GEMM: eacc[r][i] = sum_k eold[e0+r][k] * Cw[k][jbe+i]
    const float* wC = wbase + 2 * (72*WTS);
    float eacc[4][6];
    #pragma unroll
    for (int r = 0; r < 4; ++r)
      #pragma unroll
      for (int i = 0; i < 6; ++i) eacc[r][i] = 0.f;

    #pragma unroll 2
    for (int c = 0; c < 18; ++c) {
      const int k0 = c*4;
      float4 ev0 = *(const float4*)(eT + EIX(k0+0, e0));
      float4 ev1 = *(const float4*)(eT + EIX(k0+1, e0));
      float4 ev2 = *(const float4*)(eT + EIX(k0+2, e0));
      float4 ev3 = *(const float4*)(eT + EIX(k0+3, e0));
      #pragma unroll
      for (int i = 0; i < 6; ++i) {
        float4 w4 = *(const float4*)(wC + (jbe + i)*WTS + k0);
        eacc[0][i] = fmaf(ev0.x, w4.x, eacc[0][i]); eacc[1][i] = fmaf(ev0.y, w4.x, eacc[1][i]);
        eacc[2][i] = fmaf(ev0.z, w4.x, eacc[2][i]); eacc[3][i] = fmaf(ev0.w, w4.x, eacc[3][i]);
        eacc[0][i] = fmaf(ev1.x, w4.y, eacc[0][i]); eacc[1][i] = fmaf(ev1.y, w4.y, eacc[1][i]);
        eacc[2][i] = fmaf(ev1.z, w4.y, eacc[2][i]); eacc[3][i] = fmaf(ev1.w, w4.y, eacc[3][i]);
        eacc[0][i] = fmaf(ev2.x, w4.z, eacc[0][i]); eacc[1][i] = fmaf(ev2.y, w4.z, eacc[1][i]);
        eacc[2][i] = fmaf(ev2.z, w4.z, eacc[2][i]); eacc[3][i] = fmaf(ev2.w, w4.z, eacc[3][i]);
        eacc[0][i] = fmaf(ev3.x, w4.w, eacc[0][i]); eacc[1][i] = fmaf(ev3.y, w4.w, eacc[1][i]);
        eacc[2][i] = fmaf(ev3.z, w4.w, eacc[2][i]); eacc[3][i] = fmaf(ev3.w, w4.w, eacc[3][i]);
      }
    }
    __syncthreads();   // S1: Ax/Bx/Dx/Ex + SBO ready

    // ---- phase B: e-finish (float2 reads) + e-stats ----
    {
      int dl[4], sl[4];
      #pragma unroll
      for (int r = 0; r < 4; ++r) { dl[r] = dstloc[e0+r]; sl[r] = srcloc[e0+r]; }
      #pragma unroll
      for (int r = 0; r < 4; ++r) {
        const float2* dx2 = (const float2*)(Dx + dl[r]*NBS + jbe);
        const float2* ex2 = (const float2*)(Ex + sl[r]*NBS + jbe);
        float2 d0 = dx2[0], d1 = dx2[1], d2 = dx2[2];
        float2 x0 = ex2[0], x1 = ex2[1], x2 = ex2[2];
        eacc[r][0] += d0.x + x0.x; eacc[r][1] += d0.y + x0.y;
        eacc[r][2] += d1.x + x1.x; eacc[r][3] += d1.y + x1.y;
        eacc[r][4] += d2.x + x2.x; eacc[r][5] += d2.y + x2.y;
      }
      #pragma unroll
      for (int i = 0; i < 6; ++i) {
        float bb = statl[SBO + jbe + i];
        #pragma unroll
        for (int r = 0; r < 4; ++r) eacc[r][i] += bb;
      }
    }
    #pragma unroll
    for (int i = 0; i < 6; ++i) {
      int j = jbe + i;
      float ps = (eacc[0][i] + eacc[1][i]) + (eacc[2][i] + eacc[3][i]);
      float qs = eacc[0][i]*eacc[0][i];
      qs = fmaf(eacc[1][i], eacc[1][i], qs);
      qs = fmaf(eacc[2][i], eacc[2][i], qs);
      qs = fmaf(eacc[3][i], eacc[3][i], qs);
      #pragma unroll
      for (int d = 1; d < 64; d <<= 1) {
        ps += __shfl_xor(ps, d, 64);
        qs += __shfl_xor(qs, d, 64);
      }
      if (lane == 0 && j < DD) {
        atomicAdd(lslot + 140 + j, ps);
        atomicAdd(lslot + 210 + j, qs);
      }
    }
    __syncthreads();   // S2: all eT/Dx/Ex reads done (sigma overlays Dx/Ex)

    // sigma -> fp16 EDGE-MAJOR: sig[e][j], 3 half2 (u32) per edge
    #pragma unroll
    for (int r = 0; r < 4; ++r) {
      unsigned* srow = sigb + (e0 + r)*SGS + (jbe >> 1);
      #pragma unroll
      for (int t = 0; t < 3; ++t) {
        int j = jbe + 2*t;
        if (j + 1 < DD) {
          float sa = 1.f / (1.f + __expf(-eacc[r][2*t]));
          float sb = 1.f / (1.f + __expf(-eacc[r][2*t+1]));
          __half2 hh = __floats2half2_rn(sa, sb);
          srow[t] = *reinterpret_cast<unsigned*>(&hh);
        }
      }
    }
    __syncthreads();   // S3

    // ---- gather: x_new = Ax + num/den (RMW into Ax). 576 = 32 n x 18 jq ----
    if (tid < 576) {
      int n = tid / 18, jq = tid % 18;
      int j0 = jq * 4;
      bool v2 = (j0 + 2) < DD, v3 = (j0 + 3) < DD;
      float nm0 = 0.f, nm1 = 0.f, nm2 = 0.f, nm3 = 0.f;
      float dn0 = 0.f, dn1 = 0.f, dn2 = 0.f, dn3 = 0.f;
      int pb = ioff[n], pe = ioff[n + 1];
      for (int pp = pb; pp < pe; ++pp) {
        unsigned v = eidxS[pp];
        int e2 = v & 255, sl2 = v >> 8;
        uint2 sg2 = *(const uint2*)(sigb + e2*SGS + (j0 >> 1));
        __half2 p01 = *reinterpret_cast<const __half2*>(&sg2.x);
        __half2 p23 = *reinterpret_cast<const __half2*>(&sg2.y);
        float2 f01 = __half22float2(p01);
        float2 f23 = __half22float2(p23);
        float s0 = f01.x, s1 = f01.y;
        float s2 = v2 ? f23.x : 0.f;
        float s3 = v3 ? f23.y : 0.f;
        float4 b4 = *(const float4*)(Bx + sl2*NBS + j0);
        nm0 = fmaf(s0, b4.x, nm0); nm1 = fmaf(s1, b4.y, nm1);
        nm2 = fmaf(s2, b4.z, nm2); nm3 = fmaf(s3, b4.w, nm3);
        dn0 += s0; dn1 += s1; dn2 += s2; dn3 += s3;
      }
      float* axp = Ax + n*NBS + j0;
      float4 ax = *(const float4*)axp;
      ax.x += nm0 / (dn0 + EPS_AGG);
      ax.y += nm1 / (dn1 + EPS_AGG);
      ax.z += nm2 / (dn2 + EPS_AGG);
      ax.w += nm3 / (dn3 + EPS_AGG);
      *(float4*)axp = ax;
    }
    __syncthreads();   // S4

    // x-stats (280 threads: 70 cols x 4 node-quarters)
    if (tid < SPL) {
      int col = tid % DD, q = tid / DD;
      float sm = 0.f, sq = 0.f;
      #pragma unroll
      for (int r = 0; r < 8; ++r) {
        float v = Ax[(q*8 + r)*NBS + col];
        sm += v; sq = fmaf(v, v, sq);
      }
      atomicAdd(lslot + col, sm);
      atomicAdd(lslot + 70 + col, sq);
    }

    grid_sync(p.bar);

    // BN scale/shift from 8 slots
    if (tid < DD) {
      float sm = 0.f, sq = 0.f;
      #pragma unroll
      for (int sl2 = 0; sl2 < NSLOT; ++sl2) {
        const float* st = p.stats + (sl2*NLAYERS + L)*SPL;
        sm += __hip_atomic_load(st + tid,      __ATOMIC_RELAXED, __HIP_MEMORY_SCOPE_AGENT);
        sq += __hip_atomic_load(st + 70 + tid, __ATOMIC_RELAXED, __HIP_MEMORY_SCOPE_AGENT);
      }
      float mean = sm * (1.f/8192.f);
      float var  = sq * (1.f/8192.f) - mean*mean;
      float sc = p.gx[s][tid] * rsqrtf(var + EPS_BN);
      statl[SCX + tid] = sc;
      statl[SHX + tid] = fmaf(-mean, sc, p.bx[s][tid]);
    } else if (tid < 140) {
      int j = tid - DD;
      float sm = 0.f, sq = 0.f;
      #pragma unroll
      for (int sl2 = 0; sl2 < NSLOT; ++sl2) {
        const float* st = p.stats + (sl2*NLAYERS + L)*SPL;
        sm += __hip_atomic_load(st + 140 + j, __ATOMIC_RELAXED, __HIP_MEMORY_SCOPE_AGENT);
        sq += __hip_atomic_load(st + 210 + j, __ATOMIC_RELAXED, __HIP_MEMORY_SCOPE_AGENT);
      }
      float mean = sm * (1.f/65536.f);
      float var  = sq * (1.f/65536.f) - mean*mean;
      float sc = p.ge[s][j] * rsqrtf(var + EPS_BN);
      statl[SCE + j] = sc;
      statl[SHE + j] = fmaf(-mean, sc, p.gbe[s][j]);
    }
    __syncthreads();   // S5

    // apply BN+ReLU+residual: h (2304 = 3*768 exact)
    #pragma unroll
    for (int r = 0; r < 3; ++r) {
      int idx = tid + r*TPB;
      int n = idx / 72, j = idx - n*72;
      if (j < DD) {
        float xn = Ax[n*NBS + j];
        hN[n*NBS + j] += fmaxf(fmaf(xn, statl[SCX + j], statl[SHX + j]), 0.f);
      }
    }
    // apply BN+ReLU+residual: e — e_old re-read from eT (kept intact), b128 RMW
    #pragma unroll
    for (int i = 0; i < 6; ++i) {
      int j = jbe + i;
      if (j < DD) {
        float sc = statl[SCE + j], sh = statl[SHE + j];
        float* ep = eT + EIX(j, e0);
        float4 eo = *(const float4*)ep;
        eo.x += fmaxf(fmaf(eacc[0][i], sc, sh), 0.f);
        eo.y += fmaxf(fmaf(eacc[1][i], sc, sh), 0.f);
        eo.z += fmaxf(fmaf(eacc[2][i], sc, sh), 0.f);
        eo.w += fmaxf(fmaf(eacc[3][i], sc, sh), 0.f);
        *(float4*)ep = eo;
      }
    }
    __syncthreads();   // S6
  }

  // ---------------- readout ----------------
  if (tid < DD) {
    float mx = -3.4e38f, sm = 0.f;
    #pragma unroll 4
    for (int r = 0; r < 32; ++r) {
      float v = hN[r*NBS + tid];
      mx = fmaxf(mx, v); sm += v;
    }
    statl[tid]      = mx;               // gmp
    statl[70 + tid] = sm * (1.f/32.f);  // gap
  }
  __syncthreads();
  if (tid < 256) {
    float a = p.c1b[tid];
    for (int k = 0; k < DD; ++k) a = fmaf(statl[k],      p.c1w[k*256 + tid], a);
    for (int k = 0; k < DD; ++k) a = fmaf(statl[70 + k], p.c1w[(DD + k)*256 + tid], a);
    Ax[tid] = fmaxf(a, 0.f);
  }
  __syncthreads();
  if (tid == 0) {
    float sm = 0.f, sq = 0.f;
    for (int k = 0; k < 256; ++k) { float v = Ax[k]; sm += v; sq = fmaf(v, v, sq); }
    float mean = sm * (1.f/256.f);
    float var  = sq * (1.f/256.f) - mean*mean;
    statl[560] = mean;
    statl[561] = rsqrtf(var + EPS_LN);
  }
  __syncthreads();
  if (tid < 256) {
    float v = (Ax[tid] - statl[560]) * statl[561];
    Bx[tid] = fmaf(v, p.lng[tid], p.lnb[tid]);
  }
  __syncthreads();
  if (tid < 10) {
    float a = p.c2b[tid];
    for (int k = 0; k < 256; ++k) a = fmaf(Bx[k], p.c2w[k*10 + tid], a);
    p.out[g*10 + tid] = a;
  }
}

extern "C" void kernel_launch(void* const* d_in, const int* in_sizes, int n_in,
                              void* d_out, int out_size, void* d_ws, size_t ws_size,
                              hipStream_t stream) {
  (void)in_sizes; (void)n_in; (void)out_size; (void)ws_size;
  GPSParams p;
  p.x   = (const float*)d_in[0];
  p.ei  = (const int*)  d_in[1];
  p.ea  = (const float*)d_in[2];
  p.wn  = (const float*)d_in[4];  p.bnn = (const float*)d_in[5];
  p.we  = (const float*)d_in[6];  p.web = (const float*)d_in[7];
  int i = 8;
  for (int s = 0; s < 2; ++s) {
    p.Aw[s] = (const float*)d_in[i++]; p.Ab[s] = (const float*)d_in[i++];
    p.Bw[s] = (const float*)d_in[i++]; p.Bb[s] = (const float*)d_in[i++];
    p.Cw[s] = (const float*)d_in[i++]; p.Cb[s] = (const float*)d_in[i++];
    p.Dw[s] = (const float*)d_in[i++]; p.Db[s] = (const float*)d_in[i++];
    p.Ew[s] = (const float*)d_in[i++]; p.Eb[s] = (const float*)d_in[i++];
    p.gx[s] = (const float*)d_in[i++]; p.bx[s] = (const float*)d_in[i++];
    p.ge[s] = (const float*)d_in[i++]; p.gbe[s] = (const float*)d_in[i++];
  }
  p.c1w = (const float*)d_in[36]; p.c1b = (const float*)d_in[37];
  p.lng = (const float*)d_in[38]; p.lnb = (const float*)d_in[39];
  p.c2w = (const float*)d_in[40]; p.c2b = (const float*)d_in[41];
  p.out = (float*)d_out;
  p.bar = (unsigned*)d_ws;
  p.stats = (float*)((char*)d_ws + WS_STATS);
  p.wt    = (float*)((char*)d_ws + WS_WT);

  // zero barrier + stats (ws not re-poisoned between replays); wT fully
  // rewritten by the pre-pass each call.
  hipMemsetAsync(d_ws, 0, WS_STATS + NSLOT*NLAYERS*SPL*4, stream);

  hipFuncSetAttribute((const void*)gps_kernel,
                      hipFuncAttributeMaxDynamicSharedMemorySize, SMEM_BYTES);

  void* args[] = { (void*)&p };
  hipError_t err = hipLaunchCooperativeKernel((const void*)gps_kernel,
                                              dim3(NBLK), dim3(TPB),
                                              args, SMEM_BYTES, stream);
  if (err != hipSuccess) {
    gps_kernel<<<dim3(NBLK), dim3(TPB), SMEM_BYTES, stream>>>(p);
  }
}